// Round 1
// baseline (2863.957 us; speedup 1.0000x reference)
//
#include <hip/hip_runtime.h>
#include <hip/hip_bf16.h>
#include <math.h>

#define TE 32          // edges per block in k_edge
#define XS 392         // LDS stride (bf16 elems) for x tile   (word-stride % 32 == 4 -> even bank spread)
#define HS 264         // LDS stride (bf16 elems) for hidden tiles
#define HB (TE*XS)     // offset of hidden buffer (shorts)

typedef __attribute__((ext_vector_type(8))) short bf16x8;
typedef __attribute__((ext_vector_type(4))) float f32x4;

__device__ __forceinline__ unsigned short f2b(float f) {
    unsigned int x = __float_as_uint(f);
    unsigned int r = x + 0x7fffu + ((x >> 16) & 1u);   // RTNE
    return (unsigned short)(r >> 16);
}
__device__ __forceinline__ float b2f(unsigned short u) {
    return __uint_as_float(((unsigned int)u) << 16);
}
__device__ __forceinline__ float gelu_exact(float v) {
    return 0.5f * v * (1.0f + erff(v * 0.70710678118654752f));
}

// ---------------- weight prep: fp32 -> bf16, Wo transpose ----------------
__global__ void __launch_bounds__(256)
k_pre(const float* __restrict__ Wb1, const float* __restrict__ Wb2,
      const float* __restrict__ Wv1, const float* __restrict__ Wv2,
      const float* __restrict__ Wv3, const float* __restrict__ Wo,
      unsigned short* __restrict__ wbf, float* __restrict__ woT) {
    int t = blockIdx.x * 256 + threadIdx.x;
    if (t < 49152)       wbf[t] = f2b(Wb1[t]);
    else if (t < 65536)  wbf[t] = f2b(Wb2[t - 49152]);
    else if (t < 98304)  wbf[t] = f2b(Wv1[t - 65536]);
    else if (t < 114688) wbf[t] = f2b(Wv2[t - 98304]);
    else if (t < 131072) wbf[t] = f2b(Wv3[t - 114688]);
    else if (t < 147456) {
        int i = t - 131072; int j = i >> 7, k = i & 127;
        woT[k * 128 + j] = Wo[j * 128 + k];
    }
}

// ---------------- fused per-edge 3-layer MLPs (bias path + value path) ----------------
__global__ void __launch_bounds__(256)
k_edge(const float* __restrict__ hV, const float* __restrict__ hE,
       const int* __restrict__ center,
       const float* __restrict__ bv1, const float* __restrict__ bv2, const float* __restrict__ bv3,
       const float* __restrict__ bb1, const float* __restrict__ bb2,
       const float* __restrict__ Wb3, const float* __restrict__ bb3,
       const unsigned short* __restrict__ wbf,
       unsigned short* __restrict__ Vbf, float* __restrict__ ew, float* __restrict__ denom) {
    __shared__ unsigned short smem[HB + TE * HS];   // 41,984 B
    const int t = threadIdx.x;
    const int eg0 = blockIdx.x * TE;

    // ---- stage x = [h_V[center] | h_E] as bf16 into LDS, layout [e][k], stride XS ----
    #pragma unroll
    for (int i = 0; i < 8; ++i) {               // h_E part: 32 rows x 64 float4
        int vid = t + i * 256;
        int e = vid >> 6, kq = vid & 63;
        float4 g = *(const float4*)(hE + (size_t)(eg0 + e) * 256 + kq * 4);
        ushort4 p; p.x = f2b(g.x); p.y = f2b(g.y); p.z = f2b(g.z); p.w = f2b(g.w);
        *(ushort4*)&smem[e * XS + 128 + kq * 4] = p;
    }
    #pragma unroll
    for (int i = 0; i < 4; ++i) {               // h_V gather part: 32 rows x 32 float4
        int vid = t + i * 256;
        int e = vid >> 5, kq = vid & 31;
        int c = center[eg0 + e];
        float4 g = *(const float4*)(hV + (size_t)c * 128 + kq * 4);
        ushort4 p; p.x = f2b(g.x); p.y = f2b(g.y); p.z = f2b(g.z); p.w = f2b(g.w);
        *(ushort4*)&smem[e * XS + kq * 4] = p;
    }
    __syncthreads();

    const int wave = t >> 6, lane = t & 63;
    const int c16 = lane & 15, q = lane >> 4;
    const int m = wave & 1, nh = wave >> 1;
    const int e0 = m * 16;

    const unsigned short* Wb1bf = wbf;
    const unsigned short* Wb2bf = wbf + 49152;
    const unsigned short* Wv1bf = wbf + 65536;
    const unsigned short* Wv2bf = wbf + 98304;
    const unsigned short* Wv3bf = wbf + 114688;

    // ---- layer 1 ----
    bf16x8 af[12];
    #pragma unroll
    for (int ks = 0; ks < 12; ++ks)
        af[ks] = *(const bf16x8*)&smem[(e0 + c16) * XS + ks * 32 + q * 8];

    if (nh == 0) {  // bias path: K=384, features 0..127
        #pragma unroll
        for (int nt = 0; nt < 8; ++nt) {
            const int f0 = nt * 16;
            const unsigned short* wr = Wb1bf + (size_t)(f0 + c16) * 384 + q * 8;
            f32x4 acc = {0.f, 0.f, 0.f, 0.f};
            #pragma unroll
            for (int ks = 0; ks < 12; ++ks)
                acc = __builtin_amdgcn_mfma_f32_16x16x32_bf16(af[ks], *(const bf16x8*)(wr + ks * 32), acc, 0, 0, 0);
            float bias = bb1[f0 + c16];
            #pragma unroll
            for (int r = 0; r < 4; ++r)
                smem[HB + (e0 + q * 4 + r) * HS + f0 + c16] = f2b(gelu_exact(acc[r] + bias));
        }
    } else {        // value path: K=256 (x[128:384]), features 128..255
        #pragma unroll
        for (int nt = 0; nt < 8; ++nt) {
            const int f0 = nt * 16;
            const unsigned short* wr = Wv1bf + (size_t)(f0 + c16) * 256 + q * 8;
            f32x4 acc = {0.f, 0.f, 0.f, 0.f};
            #pragma unroll
            for (int ks = 0; ks < 8; ++ks)
                acc = __builtin_amdgcn_mfma_f32_16x16x32_bf16(af[4 + ks], *(const bf16x8*)(wr + ks * 32), acc, 0, 0, 0);
            float bias = bv1[f0 + c16];
            #pragma unroll
            for (int r = 0; r < 4; ++r)
                smem[HB + (e0 + q * 4 + r) * HS + 128 + f0 + c16] = f2b(gelu_exact(acc[r] + bias));
        }
    }
    __syncthreads();

    // ---- layer 2 (block-diagonal: h1b->h2b, v1->v2), output into x region ----
    bf16x8 ah[8];
    #pragma unroll
    for (int ks = 0; ks < 8; ++ks)
        ah[ks] = *(const bf16x8*)&smem[HB + (e0 + c16) * HS + ks * 32 + q * 8];

    if (nh == 0) {
        #pragma unroll
        for (int nt = 0; nt < 8; ++nt) {
            const int f0 = nt * 16;
            const unsigned short* wr = Wb2bf + (size_t)(f0 + c16) * 128 + q * 8;
            f32x4 acc = {0.f, 0.f, 0.f, 0.f};
            #pragma unroll
            for (int ks = 0; ks < 4; ++ks)
                acc = __builtin_amdgcn_mfma_f32_16x16x32_bf16(ah[ks], *(const bf16x8*)(wr + ks * 32), acc, 0, 0, 0);
            float bias = bb2[f0 + c16];
            #pragma unroll
            for (int r = 0; r < 4; ++r)
                smem[(e0 + q * 4 + r) * HS + f0 + c16] = f2b(gelu_exact(acc[r] + bias));
        }
    } else {
        #pragma unroll
        for (int nt = 0; nt < 8; ++nt) {
            const int f0 = nt * 16;
            const unsigned short* wr = Wv2bf + (size_t)(f0 + c16) * 128 + q * 8;
            f32x4 acc = {0.f, 0.f, 0.f, 0.f};
            #pragma unroll
            for (int ks = 0; ks < 4; ++ks)
                acc = __builtin_amdgcn_mfma_f32_16x16x32_bf16(ah[4 + ks], *(const bf16x8*)(wr + ks * 32), acc, 0, 0, 0);
            float bias = bv2[f0 + c16];
            #pragma unroll
            for (int r = 0; r < 4; ++r)
                smem[(e0 + q * 4 + r) * HS + 128 + f0 + c16] = f2b(gelu_exact(acc[r] + bias));
        }
    }
    __syncthreads();

    // ---- layer 3, value path via MFMA: V = v2 @ Wv3^T + bv3 (no gelu) ----
    {
        const int g = wave >> 1;
        bf16x8 av[4];
        #pragma unroll
        for (int ks = 0; ks < 4; ++ks)
            av[ks] = *(const bf16x8*)&smem[(e0 + c16) * HS + 128 + ks * 32 + q * 8];
        #pragma unroll
        for (int nn = 0; nn < 4; ++nn) {
            const int f0 = (g * 4 + nn) * 16;
            const unsigned short* wr = Wv3bf + (size_t)(f0 + c16) * 128 + q * 8;
            f32x4 acc = {0.f, 0.f, 0.f, 0.f};
            #pragma unroll
            for (int ks = 0; ks < 4; ++ks)
                acc = __builtin_amdgcn_mfma_f32_16x16x32_bf16(av[ks], *(const bf16x8*)(wr + ks * 32), acc, 0, 0, 0);
            float bias = bv3[f0 + c16];
            #pragma unroll
            for (int r = 0; r < 4; ++r)
                Vbf[(size_t)(eg0 + e0 + q * 4 + r) * 128 + f0 + c16] = f2b(acc[r] + bias);
        }
    }

    // ---- layer 3, bias path (vector): w = (h2b @ Wb3^T + bb3)/sqrt(32); ew=exp(w) ----
    if (t < 128) {
        const int e = t & 31, head = t >> 5;
        float acc = 0.f;
        #pragma unroll
        for (int kc = 0; kc < 16; ++kc) {
            bf16x8 h = *(const bf16x8*)&smem[e * HS + kc * 8];
            float4 w1 = *(const float4*)(Wb3 + head * 128 + kc * 8);
            float4 w2 = *(const float4*)(Wb3 + head * 128 + kc * 8 + 4);
            acc += b2f((unsigned short)h[0]) * w1.x + b2f((unsigned short)h[1]) * w1.y
                 + b2f((unsigned short)h[2]) * w1.z + b2f((unsigned short)h[3]) * w1.w
                 + b2f((unsigned short)h[4]) * w2.x + b2f((unsigned short)h[5]) * w2.y
                 + b2f((unsigned short)h[6]) * w2.z + b2f((unsigned short)h[7]) * w2.w;
        }
        float w = (acc + bb3[head]) * 0.17677669529663689f;  // 1/sqrt(32)
        float x = expf(w);                                    // max-subtraction-free softmax (|w|<~1)
        ew[(size_t)(eg0 + e) * 4 + head] = x;
        atomicAdd(&denom[(size_t)center[eg0 + e] * 4 + head], x);
    }
}

// ---------------- scatter: agg[c] += (ew/denom[c]) * V ----------------
__global__ void __launch_bounds__(256)
k_scatter(const unsigned short* __restrict__ Vbf, const float* __restrict__ ew,
          const float* __restrict__ denom, const int* __restrict__ center,
          float* __restrict__ agg) {
    int t = blockIdx.x * 256 + threadIdx.x;      // E*32 threads
    int e = t >> 5, qq = t & 31;
    int j0 = qq * 4, head = qq >> 3;
    int c = center[e];
    float a = ew[(size_t)e * 4 + head] / denom[(size_t)c * 4 + head];
    ushort4 v = *(const ushort4*)(Vbf + (size_t)e * 128 + j0);
    float* dst = agg + (size_t)c * 128 + j0;
    atomicAdd(dst + 0, a * b2f(v.x));
    atomicAdd(dst + 1, a * b2f(v.y));
    atomicAdd(dst + 2, a * b2f(v.z));
    atomicAdd(dst + 3, a * b2f(v.w));
}

// ---------------- out = agg @ Wo^T (fp32, Wo pre-transposed for coalescing) ----------------
__global__ void __launch_bounds__(256)
k_out(const float* __restrict__ agg, const float* __restrict__ woT, float* __restrict__ out) {
    __shared__ float arow[8 * 128];
    int t = threadIdx.x; int n0 = blockIdx.x * 8;
    *(float4*)&arow[t * 4] = *(const float4*)(agg + (size_t)n0 * 128 + t * 4);
    __syncthreads();
    int j = t & 127, half = t >> 7;
    float a0 = 0.f, a1 = 0.f, a2 = 0.f, a3 = 0.f;
    for (int k = 0; k < 128; ++k) {
        float w = woT[k * 128 + j];
        a0 += w * arow[(half * 4 + 0) * 128 + k];
        a1 += w * arow[(half * 4 + 1) * 128 + k];
        a2 += w * arow[(half * 4 + 2) * 128 + k];
        a3 += w * arow[(half * 4 + 3) * 128 + k];
    }
    out[(size_t)(n0 + half * 4 + 0) * 128 + j] = a0;
    out[(size_t)(n0 + half * 4 + 1) * 128 + j] = a1;
    out[(size_t)(n0 + half * 4 + 2) * 128 + j] = a2;
    out[(size_t)(n0 + half * 4 + 3) * 128 + j] = a3;
}

extern "C" void kernel_launch(void* const* d_in, const int* in_sizes, int n_in,
                              void* d_out, int out_size, void* d_ws, size_t ws_size,
                              hipStream_t stream) {
    const float* hV  = (const float*)d_in[0];
    const float* hE  = (const float*)d_in[1];
    const float* Wv1 = (const float*)d_in[2];
    const float* bv1 = (const float*)d_in[3];
    const float* Wv2 = (const float*)d_in[4];
    const float* bv2 = (const float*)d_in[5];
    const float* Wv3 = (const float*)d_in[6];
    const float* bv3 = (const float*)d_in[7];
    const float* Wb1 = (const float*)d_in[8];
    const float* bb1 = (const float*)d_in[9];
    const float* Wb2 = (const float*)d_in[10];
    const float* bb2 = (const float*)d_in[11];
    const float* Wb3 = (const float*)d_in[12];
    const float* bb3 = (const float*)d_in[13];
    const float* Wo  = (const float*)d_in[14];
    const int* center = (const int*)d_in[15];
    float* out = (float*)d_out;

    char* ws = (char*)d_ws;
    unsigned short* wbf = (unsigned short*)(ws + 0);          // 131072 bf16 weights
    float* woT   = (float*)(ws + 262144);                      // 16384 f32
    float* denom = (float*)(ws + 327680);                      // 20000*4 f32
    float* agg   = (float*)(ws + 647680);                      // 20000*128 f32
    float* ew    = (float*)(ws + 10887680);                    // 600000*4 f32
    unsigned short* Vbf = (unsigned short*)(ws + 20487680);    // 600000*128 bf16

    hipMemsetAsync(ws + 327680, 0, 10560000, stream);          // zero denom + agg
    k_pre<<<576, 256, 0, stream>>>(Wb1, Wb2, Wv1, Wv2, Wv3, Wo, wbf, woT);
    k_edge<<<600000 / TE, 256, 0, stream>>>(hV, hE, center, bv1, bv2, bv3,
                                            bb1, bb2, Wb3, bb3, wbf, Vbf, ew, denom);
    k_scatter<<<600000 * 32 / 256, 256, 0, stream>>>(Vbf, ew, denom, center, agg);
    k_out<<<20000 / 8, 256, 0, stream>>>(agg, woT, out);
}

// Round 3
// 1473.881 us; speedup vs baseline: 1.9431x; 1.9431x over previous
//
#include <hip/hip_runtime.h>
#include <hip/hip_bf16.h>
#include <math.h>

#define TE 32
#define XS 392          // x tile stride (shorts)
#define HS 264          // hidden tile stride (shorts)
#define NTILES 18750    // 600000 / TE

typedef __attribute__((ext_vector_type(8))) short bf16x8;
typedef __attribute__((ext_vector_type(4))) float f32x4;

__device__ __forceinline__ unsigned short f2b(float f) {
    unsigned int x = __float_as_uint(f);
    unsigned int r = x + 0x7fffu + ((x >> 16) & 1u);   // RTNE
    return (unsigned short)(r >> 16);
}
__device__ __forceinline__ float b2f(unsigned short u) {
    return __uint_as_float(((unsigned int)u) << 16);
}
__device__ __forceinline__ float gelu_exact(float v) {
    return 0.5f * v * (1.0f + erff(v * 0.70710678118654752f));
}

// ---------------- weight prep: fp32 -> bf16, Wo transpose ----------------
__global__ void __launch_bounds__(256)
k_pre(const float* __restrict__ Wb1, const float* __restrict__ Wb2,
      const float* __restrict__ Wv1, const float* __restrict__ Wv2,
      const float* __restrict__ Wv3, const float* __restrict__ Wo,
      unsigned short* __restrict__ wbf, float* __restrict__ woT) {
    int t = blockIdx.x * 256 + threadIdx.x;
    if (t < 49152)       wbf[t] = f2b(Wb1[t]);
    else if (t < 65536)  wbf[t] = f2b(Wb2[t - 49152]);
    else if (t < 98304)  wbf[t] = f2b(Wv1[t - 65536]);
    else if (t < 114688) wbf[t] = f2b(Wv2[t - 98304]);
    else if (t < 131072) wbf[t] = f2b(Wv3[t - 114688]);
    else if (t < 147456) {
        int i = t - 131072; int j = i >> 7, k = i & 127;
        woT[k * 128 + j] = Wo[j * 128 + k];
    }
}

// ---------------- CSR build ----------------
__global__ void __launch_bounds__(256)
k_hist(const int* __restrict__ center, int* __restrict__ counts) {
    int t = blockIdx.x * 256 + threadIdx.x;
    if (t < 600000) atomicAdd(&counts[center[t]], 1);
}

__global__ void __launch_bounds__(256)
k_scan(const int* __restrict__ counts, int* __restrict__ offsets,
       int* __restrict__ cursor, int n) {
    __shared__ int buf[256];
    __shared__ int carry;
    int t = threadIdx.x;
    if (t == 0) carry = 0;
    __syncthreads();
    for (int base = 0; base < n; base += 256) {
        int v = (base + t < n) ? counts[base + t] : 0;
        buf[t] = v; __syncthreads();
        for (int off = 1; off < 256; off <<= 1) {
            int x = (t >= off) ? buf[t - off] : 0;
            __syncthreads();
            buf[t] += x;
            __syncthreads();
        }
        int excl = carry + buf[t] - v;
        if (base + t < n) { offsets[base + t] = excl; cursor[base + t] = excl; }
        int tot = buf[255];
        __syncthreads();
        if (t == 0) carry += tot;
        __syncthreads();
    }
}

__global__ void __launch_bounds__(256)
k_place(const int* __restrict__ center, int* __restrict__ cursor, int* __restrict__ eidx) {
    int t = blockIdx.x * 256 + threadIdx.x;
    if (t < 600000) {
        int p = atomicAdd(&cursor[center[t]], 1);
        eidx[p] = t;
    }
}

// ---------------- staging helper: x = [bf16(h_V[center]) | bf16(h_E)] ----------------
__device__ __forceinline__ void stage_tile(int t, int eg0,
        const float* __restrict__ hE, const float* __restrict__ hV,
        const int* __restrict__ center, unsigned short* __restrict__ xs) {
    #pragma unroll
    for (int i = 0; i < 4; ++i) {               // h_E: 32 rows x 64 float4
        int vid = t + i * 512;
        int e = vid >> 6, kq = vid & 63;
        float4 g = *(const float4*)(hE + (size_t)(eg0 + e) * 256 + kq * 4);
        ushort4 p; p.x = f2b(g.x); p.y = f2b(g.y); p.z = f2b(g.z); p.w = f2b(g.w);
        *(ushort4*)&xs[e * XS + 128 + kq * 4] = p;
    }
    #pragma unroll
    for (int i = 0; i < 2; ++i) {               // h_V gather: 32 rows x 32 float4
        int vid = t + i * 512;
        int e = vid >> 5, kq = vid & 31;
        int c = center[eg0 + e];
        float4 g = *(const float4*)(hV + (size_t)c * 128 + kq * 4);
        ushort4 p; p.x = f2b(g.x); p.y = f2b(g.y); p.z = f2b(g.z); p.w = f2b(g.w);
        *(ushort4*)&xs[e * XS + kq * 4] = p;
    }
}

// ---------------- fused per-edge MLPs: persistent, weights in VGPRs ----------------
__global__ void __launch_bounds__(512, 2)
k_edge(const float* __restrict__ hV, const float* __restrict__ hE,
       const int* __restrict__ center,
       const float* __restrict__ bv1, const float* __restrict__ bv2, const float* __restrict__ bv3,
       const float* __restrict__ bb1, const float* __restrict__ bb2,
       const float* __restrict__ Wb3, const float* __restrict__ bb3,
       const unsigned short* __restrict__ wbf,
       unsigned short* __restrict__ Vbf, float* __restrict__ ew, float* __restrict__ denom)
{
    __shared__ unsigned short smem[29440];   // xs[32*392] + h1[32*264] + h2[32*264]
    __shared__ float wb3s[512];
    const int t = threadIdx.x;
    const int wave = t >> 6, lane = t & 63;
    const int c16 = lane & 15, q = lane >> 4;
    wb3s[t] = Wb3[t];                        // 512 threads, 512 elems

    unsigned short* xs = smem;               // [32][XS]
    unsigned short* h1 = smem + 12544;       // [32][HS]
    unsigned short* h2 = smem + 20992;       // [32][HS]

    const unsigned short* Wb1bf = wbf;
    const unsigned short* Wb2bf = wbf + 49152;
    const unsigned short* Wv1bf = wbf + 65536;
    const unsigned short* Wv2bf = wbf + 98304;
    const unsigned short* Wv3bf = wbf + 114688;

    if (wave < 4) {
        // ================= bias path: features fb..fb+31 =================
        const int fb = wave * 32;
        bf16x8 wb1[2][12], wb2[2][4];
        float bias1[2], bias2[2];
        #pragma unroll
        for (int nt = 0; nt < 2; ++nt) {
            const int fr = fb + nt * 16 + c16;
            #pragma unroll
            for (int ks = 0; ks < 12; ++ks)
                wb1[nt][ks] = *(const bf16x8*)(Wb1bf + (size_t)fr * 384 + ks * 32 + q * 8);
            #pragma unroll
            for (int ks = 0; ks < 4; ++ks)
                wb2[nt][ks] = *(const bf16x8*)(Wb2bf + (size_t)fr * 128 + ks * 32 + q * 8);
            bias1[nt] = bb1[fr]; bias2[nt] = bb2[fr];
        }
        for (int tile = blockIdx.x; tile < NTILES; tile += gridDim.x) {
            const int eg0 = tile * TE;
            stage_tile(t, eg0, hE, hV, center, xs);
            __syncthreads();
            // ---- L1: h1b = gelu(x @ Wb1^T + bb1), K=384 ----
            #pragma unroll
            for (int m = 0; m < 2; ++m) {
                bf16x8 af[12];
                #pragma unroll
                for (int ks = 0; ks < 12; ++ks)
                    af[ks] = *(const bf16x8*)&xs[(m * 16 + c16) * XS + ks * 32 + q * 8];
                f32x4 a0 = {0.f,0.f,0.f,0.f}, a1 = {0.f,0.f,0.f,0.f};
                #pragma unroll
                for (int ks = 0; ks < 12; ++ks) {
                    a0 = __builtin_amdgcn_mfma_f32_16x16x32_bf16(af[ks], wb1[0][ks], a0, 0, 0, 0);
                    a1 = __builtin_amdgcn_mfma_f32_16x16x32_bf16(af[ks], wb1[1][ks], a1, 0, 0, 0);
                }
                #pragma unroll
                for (int r = 0; r < 4; ++r) {
                    int row = (m * 16 + q * 4 + r) * HS;
                    h1[row + fb + c16]      = f2b(gelu_exact(a0[r] + bias1[0]));
                    h1[row + fb + 16 + c16] = f2b(gelu_exact(a1[r] + bias1[1]));
                }
            }
            __syncthreads();
            // ---- L2: h2b = gelu(h1b @ Wb2^T + bb2), K=128 ----
            #pragma unroll
            for (int m = 0; m < 2; ++m) {
                bf16x8 ah[4];
                #pragma unroll
                for (int ks = 0; ks < 4; ++ks)
                    ah[ks] = *(const bf16x8*)&h1[(m * 16 + c16) * HS + ks * 32 + q * 8];
                f32x4 a0 = {0.f,0.f,0.f,0.f}, a1 = {0.f,0.f,0.f,0.f};
                #pragma unroll
                for (int ks = 0; ks < 4; ++ks) {
                    a0 = __builtin_amdgcn_mfma_f32_16x16x32_bf16(ah[ks], wb2[0][ks], a0, 0, 0, 0);
                    a1 = __builtin_amdgcn_mfma_f32_16x16x32_bf16(ah[ks], wb2[1][ks], a1, 0, 0, 0);
                }
                #pragma unroll
                for (int r = 0; r < 4; ++r) {
                    int row = (m * 16 + q * 4 + r) * HS;
                    h2[row + fb + c16]      = f2b(gelu_exact(a0[r] + bias2[0]));
                    h2[row + fb + 16 + c16] = f2b(gelu_exact(a1[r] + bias2[1]));
                }
            }
            __syncthreads();
            // ---- L3 (waves 0,1): logits -> ew, denom atomics ----
            if (t < 128) {
                const int e = t & 31, head = t >> 5;
                float acc = 0.f;
                #pragma unroll
                for (int kc = 0; kc < 16; ++kc) {
                    bf16x8 h = *(const bf16x8*)&h2[e * HS + kc * 8];
                    #pragma unroll
                    for (int j = 0; j < 8; ++j)
                        acc += b2f((unsigned short)h[j]) * wb3s[head * 128 + kc * 8 + j];
                }
                float w = (acc + bb3[head]) * 0.17677669529663689f;   // 1/sqrt(32)
                float xv = expf(w);                                    // |w| small: no max-sub needed
                ew[(size_t)(eg0 + e) * 4 + head] = xv;
                atomicAdd(&denom[(size_t)center[eg0 + e] * 4 + head], xv);
            }
        }
    } else {
        // ================= value path: features fv..fv+31 =================
        const int fv = (wave - 4) * 32;
        bf16x8 wv1[2][8], wv2[2][4], wv3[2][4];
        float bias1[2], bias2[2], bias3[2];
        #pragma unroll
        for (int nt = 0; nt < 2; ++nt) {
            const int fr = fv + nt * 16 + c16;
            #pragma unroll
            for (int ks = 0; ks < 8; ++ks)
                wv1[nt][ks] = *(const bf16x8*)(Wv1bf + (size_t)fr * 256 + ks * 32 + q * 8);
            #pragma unroll
            for (int ks = 0; ks < 4; ++ks) {
                wv2[nt][ks] = *(const bf16x8*)(Wv2bf + (size_t)fr * 128 + ks * 32 + q * 8);
                wv3[nt][ks] = *(const bf16x8*)(Wv3bf + (size_t)fr * 128 + ks * 32 + q * 8);
            }
            bias1[nt] = bv1[fr]; bias2[nt] = bv2[fr]; bias3[nt] = bv3[fr];
        }
        for (int tile = blockIdx.x; tile < NTILES; tile += gridDim.x) {
            const int eg0 = tile * TE;
            stage_tile(t, eg0, hE, hV, center, xs);
            __syncthreads();
            // ---- L1: v1 = gelu(h_E @ Wv1^T + bv1), K=256 (x cols 128..383) ----
            #pragma unroll
            for (int m = 0; m < 2; ++m) {
                bf16x8 af[8];
                #pragma unroll
                for (int ks = 0; ks < 8; ++ks)
                    af[ks] = *(const bf16x8*)&xs[(m * 16 + c16) * XS + 128 + ks * 32 + q * 8];
                f32x4 a0 = {0.f,0.f,0.f,0.f}, a1 = {0.f,0.f,0.f,0.f};
                #pragma unroll
                for (int ks = 0; ks < 8; ++ks) {
                    a0 = __builtin_amdgcn_mfma_f32_16x16x32_bf16(af[ks], wv1[0][ks], a0, 0, 0, 0);
                    a1 = __builtin_amdgcn_mfma_f32_16x16x32_bf16(af[ks], wv1[1][ks], a1, 0, 0, 0);
                }
                #pragma unroll
                for (int r = 0; r < 4; ++r) {
                    int row = (m * 16 + q * 4 + r) * HS;
                    h1[row + 128 + fv + c16]      = f2b(gelu_exact(a0[r] + bias1[0]));
                    h1[row + 128 + fv + 16 + c16] = f2b(gelu_exact(a1[r] + bias1[1]));
                }
            }
            __syncthreads();
            // ---- L2: v2 = gelu(v1 @ Wv2^T + bv2), K=128 ----
            #pragma unroll
            for (int m = 0; m < 2; ++m) {
                bf16x8 ah[4];
                #pragma unroll
                for (int ks = 0; ks < 4; ++ks)
                    ah[ks] = *(const bf16x8*)&h1[(m * 16 + c16) * HS + 128 + ks * 32 + q * 8];
                f32x4 a0 = {0.f,0.f,0.f,0.f}, a1 = {0.f,0.f,0.f,0.f};
                #pragma unroll
                for (int ks = 0; ks < 4; ++ks) {
                    a0 = __builtin_amdgcn_mfma_f32_16x16x32_bf16(ah[ks], wv2[0][ks], a0, 0, 0, 0);
                    a1 = __builtin_amdgcn_mfma_f32_16x16x32_bf16(ah[ks], wv2[1][ks], a1, 0, 0, 0);
                }
                #pragma unroll
                for (int r = 0; r < 4; ++r) {
                    int row = (m * 16 + q * 4 + r) * HS;
                    h2[row + 128 + fv + c16]      = f2b(gelu_exact(a0[r] + bias2[0]));
                    h2[row + 128 + fv + 16 + c16] = f2b(gelu_exact(a1[r] + bias2[1]));
                }
            }
            __syncthreads();
            // ---- L3: V = v2 @ Wv3^T + bv3 -> Vbf (global, bf16) ----
            #pragma unroll
            for (int m = 0; m < 2; ++m) {
                bf16x8 av[4];
                #pragma unroll
                for (int ks = 0; ks < 4; ++ks)
                    av[ks] = *(const bf16x8*)&h2[(m * 16 + c16) * HS + 128 + ks * 32 + q * 8];
                f32x4 a0 = {0.f,0.f,0.f,0.f}, a1 = {0.f,0.f,0.f,0.f};
                #pragma unroll
                for (int ks = 0; ks < 4; ++ks) {
                    a0 = __builtin_amdgcn_mfma_f32_16x16x32_bf16(av[ks], wv3[0][ks], a0, 0, 0, 0);
                    a1 = __builtin_amdgcn_mfma_f32_16x16x32_bf16(av[ks], wv3[1][ks], a1, 0, 0, 0);
                }
                #pragma unroll
                for (int r = 0; r < 4; ++r) {
                    size_t row = (size_t)(eg0 + m * 16 + q * 4 + r) * 128;
                    Vbf[row + fv + c16]      = f2b(a0[r] + bias3[0]);
                    Vbf[row + fv + 16 + c16] = f2b(a1[r] + bias3[1]);
                }
            }
        }
    }
}

// -------- fused gather+output: agg(node) in LDS, then out = agg @ Wo^T --------
__global__ void __launch_bounds__(256)
k_gather_out(const unsigned short* __restrict__ Vbf, const float* __restrict__ ew,
             const float* __restrict__ denom, const int* __restrict__ offsets,
             const int* __restrict__ counts, const int* __restrict__ eidx,
             const float* __restrict__ woT, float* __restrict__ out)
{
    __shared__ float aggs[4][128];
    const int t = threadIdx.x;
    const int node = blockIdx.x * 4 + (t >> 6);
    const int lane = t & 63;
    const int j = lane * 2, head = j >> 5;
    // --- gather: attention-weighted sum of V rows for this node ---
    {
        int off = offsets[node], deg = counts[node];
        float den = denom[(size_t)node * 4 + head];
        float dinv = (den != 0.f) ? (1.f / den) : 0.f;
        float a0 = 0.f, a1 = 0.f;
        for (int i = 0; i < deg; ++i) {
            int e = eidx[off + i];
            float at = ew[(size_t)e * 4 + head] * dinv;
            ushort2 v = *(const ushort2*)(Vbf + (size_t)e * 128 + j);
            a0 += at * b2f(v.x);
            a1 += at * b2f(v.y);
        }
        aggs[t >> 6][j]     = a0;
        aggs[t >> 6][j + 1] = a1;
    }
    __syncthreads();
    // --- output: out[n][c] = sum_k aggs[n][k] * Wo[c][k]  (woT[k*128+c]) ---
    {
        const int c = t & 127, nh = t >> 7;     // nh in {0,1}: nodes {nh, nh+2}
        float o0 = 0.f, o1 = 0.f;
        for (int k = 0; k < 128; ++k) {
            float w = woT[k * 128 + c];
            o0 += w * aggs[nh][k];
            o1 += w * aggs[nh + 2][k];
        }
        out[(size_t)(blockIdx.x * 4 + nh) * 128 + c]     = o0;
        out[(size_t)(blockIdx.x * 4 + nh + 2) * 128 + c] = o1;
    }
}

extern "C" void kernel_launch(void* const* d_in, const int* in_sizes, int n_in,
                              void* d_out, int out_size, void* d_ws, size_t ws_size,
                              hipStream_t stream) {
    const float* hV  = (const float*)d_in[0];
    const float* hE  = (const float*)d_in[1];
    const float* Wv1 = (const float*)d_in[2];
    const float* bv1 = (const float*)d_in[3];
    const float* Wv2 = (const float*)d_in[4];
    const float* bv2 = (const float*)d_in[5];
    const float* Wv3 = (const float*)d_in[6];
    const float* bv3 = (const float*)d_in[7];
    const float* Wb1 = (const float*)d_in[8];
    const float* bb1 = (const float*)d_in[9];
    const float* Wb2 = (const float*)d_in[10];
    const float* bb2 = (const float*)d_in[11];
    const float* Wb3 = (const float*)d_in[12];
    const float* bb3 = (const float*)d_in[13];
    const float* Wo  = (const float*)d_in[14];
    const int* center = (const int*)d_in[15];
    float* out = (float*)d_out;

    // ---- workspace layout (peak 166,487,680 B — below Round-1-proven 174 MB) ----
    char* ws = (char*)d_ws;
    unsigned short* wbf = (unsigned short*)(ws + 0);          // 131072 bf16  (262144 B)
    float* woT     = (float*)(ws + 262144);                   // 16384 f32    (65536 B)
    float* denom   = (float*)(ws + 327680);                   // 80000 f32    (320000 B)
    int*   counts  = (int*)  (ws + 647680);                   // 20000        (80000 B)
    int*   offsets = (int*)  (ws + 727680);                   // 20000        (80000 B)
    int*   cursor  = (int*)  (ws + 807680);                   // 20000        (80000 B)
    int*   eidx    = (int*)  (ws + 887680);                   // 600000       (2400000 B)
    float* ew      = (float*)(ws + 3287680);                  // 2400000 f32  (9600000 B)
    unsigned short* Vbf = (unsigned short*)(ws + 12887680);   // 76800000 bf16 (153600000 B)

    hipMemsetAsync(ws + 327680, 0, 400000, stream);           // zero denom + counts
    k_pre  <<<576, 256, 0, stream>>>(Wb1, Wb2, Wv1, Wv2, Wv3, Wo, wbf, woT);
    k_hist <<<2344, 256, 0, stream>>>(center, counts);
    k_scan <<<1, 256, 0, stream>>>(counts, offsets, cursor, 20000);
    k_place<<<2344, 256, 0, stream>>>(center, cursor, eidx);
    k_edge <<<512, 512, 0, stream>>>(hV, hE, center, bv1, bv2, bv3,
                                     bb1, bb2, Wb3, bb3, wbf, Vbf, ew, denom);
    k_gather_out<<<5000, 256, 0, stream>>>(Vbf, ew, denom, offsets, counts, eidx, woT, out);
}